// Round 10
// baseline (159.475 us; speedup 1.0000x reference)
//
#include <hip/hip_runtime.h>
#include <hip/hip_bf16.h>

#define WIN   9
#define NB    8
#define LL    4096
#define CC    256
#define UU    256
#define NW    (LL - WIN + 1)   // 4088
#define WB    56               // windows per block (73*56 = 4088 exactly)
#define RB    64               // rows per block = WB + 8 halo = 4*16
#define JB    73               // blocks per batch

typedef unsigned short ushort;
typedef __attribute__((ext_vector_type(8))) unsigned short ushort8v;
typedef __attribute__((ext_vector_type(4))) unsigned short ushort4v;
typedef __attribute__((ext_vector_type(8))) short short8v;
typedef __attribute__((ext_vector_type(4))) float f32x4;

__device__ __forceinline__ float bf16_to_f(ushort u) {
    return __uint_as_float(((unsigned int)u) << 16);
}
__device__ __forceinline__ ushort f2bf(float f) {
    __hip_bfloat16 h = __float2bfloat16(f);
    return *reinterpret_cast<ushort*>(&h);
}
__device__ __forceinline__ float fast_tanh(float x) {
    float e = __expf(2.0f * x);
    return 1.0f - 2.0f * __builtin_amdgcn_rcpf(e + 1.0f);
}
// 16B-chunk swizzles (chunk index c in [0,32), row r).
// SW (As/CK/CQ): rotate maps logical 2t/2t+1 -> t / 16+t (both parities) ->
// attn-phase 16-lane ds_read_b128 lands on 16 distinct chunk&7 groups = floor.
__device__ __forceinline__ int SW(int c, int r) {
    return (((c & 1) << 4) | (c >> 1)) ^ (r & 7);
}

// ---------------- P1: W [c][u] fp32 -> WT [u][c] bf16 (combined [512][256]) --
__global__ __launch_bounds__(256) void transpose_w(const float* __restrict__ Wk,
                                                   const float* __restrict__ Wq,
                                                   ushort* __restrict__ WkT,
                                                   ushort* __restrict__ WqT) {
    const float* W = blockIdx.z ? Wq : Wk;
    ushort* O = blockIdx.z ? WqT : WkT;
    __shared__ float t[32][33];
    int c0 = blockIdx.x * 32, u0 = blockIdx.y * 32;
    int tr = threadIdx.x >> 3, tc = (threadIdx.x & 7) * 4;
    float4 v = *reinterpret_cast<const float4*>(&W[(size_t)(c0 + tr) * UU + u0 + tc]);
    t[tr][tc + 0] = v.x; t[tr][tc + 1] = v.y; t[tr][tc + 2] = v.z; t[tr][tc + 3] = v.w;
    __syncthreads();
    ushort4v o;
    #pragma unroll
    for (int i = 0; i < 4; ++i) o[i] = f2bf(t[tc + i][tr]);
    *reinterpret_cast<ushort4v*>(&O[(size_t)(u0 + tr) * CC + c0 + tc]) = o;
}

// ---------------- Fused: stage A -> GEMM K|Q into LDS -> attn -> out ---------
// Block: 56 windows, rows [w0, w0+64). 512 thr = 8 waves.
// GEMM: wave tile M16 x N32 (waves: 4M x 2N) over combined N=512 in 8 slices.
// LDS: As 32K + Bs 32K + CK 32K + CQ 32K = 128 KB (1 block/CU).
__global__ __launch_bounds__(512, 1) void fused_smoother(
    const float* __restrict__ X,
    const ushort* __restrict__ WTall,
    const float* __restrict__ v,
    const float* __restrict__ b,
    float* __restrict__ out)
{
    __shared__ ushort As[RB * CC];
    __shared__ ushort Bs[64 * CC];
    __shared__ ushort CK[RB * CC];
    __shared__ ushort CQ[RB * CC];

    const int bid = blockIdx.x;           // < 584
    const int n   = bid & 7;              // batch -> XCD-contiguous windows
    const int j   = bid >> 3;             // 0..72
    const int w0  = j * WB;

    const int tid  = threadIdx.x;
    const int wid  = tid >> 6;
    const int lane = tid & 63;

    // ---- stage A: X rows [w0, w0+64) fp32 -> bf16, swizzled ds_write --------
    const float* xbase = X + ((size_t)n * LL + w0) * CC;
    #pragma unroll
    for (int i = 0; i < 4; ++i) {
        int cid = i * 512 + tid;          // 0..2047 = 64 rows x 32 chunks
        int row = cid >> 5, ch = cid & 31;
        const float* src = xbase + row * CC + ch * 8;
        float4 f0 = *reinterpret_cast<const float4*>(src);
        float4 f1 = *reinterpret_cast<const float4*>(src + 4);
        ushort8v o;
        o[0] = f2bf(f0.x); o[1] = f2bf(f0.y); o[2] = f2bf(f0.z); o[3] = f2bf(f0.w);
        o[4] = f2bf(f1.x); o[5] = f2bf(f1.y); o[6] = f2bf(f1.z); o[7] = f2bf(f1.w);
        *reinterpret_cast<ushort8v*>(&As[row * CC + SW(ch, row) * 8]) = o;
    }
    __syncthreads();

    // ---- preload A fragments: wave M-tile at m0w, reused across all slices --
    const int m0w  = (wid & 3) * 16;
    const int n0w  = (wid >> 2) * 32;
    const int lrow = lane & 15;
    const int lkc  = lane >> 4;           // 0..3
    short8v af[8];
    {
        int r = m0w + lrow;
        #pragma unroll
        for (int k8 = 0; k8 < 8; ++k8) {
            int cl = k8 * 4 + lkc;
            af[k8] = *reinterpret_cast<const short8v*>(&As[r * CC + SW(cl, r) * 8]);
        }
    }

    // ---- GEMM: 8 slices of 64 combined-cols, B single-buffered DMA ----------
    const int srow = tid >> 5;            // for staging addr comment only
    (void)srow;
    for (int s = 0; s < 8; ++s) {
        if (s) __syncthreads();           // prior slice's Bs reads complete
        const int s0 = s * 64;
        #pragma unroll
        for (int i = 0; i < 4; ++i) {
            int gc = i * 512 + tid;       // 0..2047 = 64 rows x 32 chunks
            int row = gc >> 5, ch = gc & 31;
            int ca  = ch ^ (row & 7);     // inverse-swizzled global source
            const ushort* src = WTall + (size_t)(s0 + row) * CC + ca * 8;
            ushort* dst = &Bs[(size_t)(i * 512 + wid * 64) * 8]; // wave-uniform
            __builtin_amdgcn_global_load_lds(
                (const __attribute__((address_space(1))) void*)src,
                (__attribute__((address_space(3))) void*)dst, 16, 0, 0);
        }
        __syncthreads();                  // vmcnt drained -> Bs ready

        f32x4 acc0 = {}, acc1 = {};
        #pragma unroll
        for (int k8 = 0; k8 < 8; ++k8) {
            int cl  = k8 * 4 + lkc;
            int rb0 = n0w + lrow;
            int rb1 = n0w + 16 + lrow;
            short8v b0 = *reinterpret_cast<const short8v*>(&Bs[rb0 * CC + ((cl ^ (rb0 & 7)) * 8)]);
            short8v b1 = *reinterpret_cast<const short8v*>(&Bs[rb1 * CC + ((cl ^ (rb1 & 7)) * 8)]);
            acc0 = __builtin_amdgcn_mfma_f32_16x16x32_bf16(af[k8], b0, acc0, 0, 0, 0);
            acc1 = __builtin_amdgcn_mfma_f32_16x16x32_bf16(af[k8], b1, acc1, 0, 0, 0);
        }
        // epilogue: C col = s0+n0w+nf*16+(lane&15), row = m0w+(lane>>4)*4+j
        ushort* Cdst = (s0 + n0w < 256) ? CK : CQ;
        const int colb = (s0 + n0w) & 255;
        #pragma unroll
        for (int nf = 0; nf < 2; ++nf) {
            const f32x4 a = nf ? acc1 : acc0;
            #pragma unroll
            for (int jj = 0; jj < 4; ++jj) {
                int rc  = m0w + (lane >> 4) * 4 + jj;
                int col = colb + nf * 16 + lrow;
                Cdst[rc * CC + SW(col >> 3, rc) * 8 + (col & 7)] = f2bf(a[jj]);
            }
        }
    }
    __syncthreads();                      // all CK/CQ writes visible

    // ---- attention: 32 groups of 16 lanes; lane t owns u/c = 16t..16t+15 ----
    const int g = tid >> 4;               // 0..31
    const int t = tid & 15;
    const int u0 = t * 16;

    float vv[16], bb[16];
    #pragma unroll
    for (int i = 0; i < 4; ++i) {
        *reinterpret_cast<float4*>(&vv[i * 4]) = *reinterpret_cast<const float4*>(v + u0 + i * 4);
        *reinterpret_cast<float4*>(&bb[i * 4]) = *reinterpret_cast<const float4*>(b + u0 + i * 4);
    }

    for (int wl = g; wl < WB; wl += 32) {
        const int qr = wl + 4;
        ushort8v q0 = *reinterpret_cast<const ushort8v*>(&CQ[qr * CC + SW(2 * t, qr) * 8]);
        ushort8v q1 = *reinterpret_cast<const ushort8v*>(&CQ[qr * CC + SW(2 * t + 1, qr) * 8]);
        float qb[16];
        #pragma unroll
        for (int i = 0; i < 8; ++i) {
            qb[i]     = bf16_to_f(q0[i]) + bb[i];
            qb[8 + i] = bf16_to_f(q1[i]) + bb[8 + i];
        }

        float p[WIN];
        #pragma unroll
        for (int s = 0; s < WIN; ++s) {
            const int kr = wl + s;
            ushort8v k0 = *reinterpret_cast<const ushort8v*>(&CK[kr * CC + SW(2 * t, kr) * 8]);
            ushort8v k1 = *reinterpret_cast<const ushort8v*>(&CK[kr * CC + SW(2 * t + 1, kr) * 8]);
            float a = 0.0f;
            #pragma unroll
            for (int i = 0; i < 8; ++i) {
                a += vv[i]     * fast_tanh(qb[i]     + bf16_to_f(k0[i]));
                a += vv[8 + i] * fast_tanh(qb[8 + i] + bf16_to_f(k1[i]));
            }
            p[s] = a;
        }
        #pragma unroll
        for (int off = 8; off; off >>= 1)
            #pragma unroll
            for (int s = 0; s < WIN; ++s)
                p[s] += __shfl_xor(p[s], off);

        float m = p[0];
        #pragma unroll
        for (int s = 1; s < WIN; ++s) m = fmaxf(m, p[s]);
        float e[WIN];
        float sum = 0.0f;
        #pragma unroll
        for (int s = 0; s < WIN; ++s) { e[s] = __expf(p[s] - m); sum += e[s]; }
        float inv = 1.0f / sum;

        float acc[16] = {};
        #pragma unroll
        for (int s = 0; s < WIN; ++s) {
            float ws = e[s] * inv;
            const int ar = wl + s;
            ushort8v x0 = *reinterpret_cast<const ushort8v*>(&As[ar * CC + SW(2 * t, ar) * 8]);
            ushort8v x1 = *reinterpret_cast<const ushort8v*>(&As[ar * CC + SW(2 * t + 1, ar) * 8]);
            #pragma unroll
            for (int i = 0; i < 8; ++i) {
                acc[i]     = fmaf(ws, bf16_to_f(x0[i]), acc[i]);
                acc[8 + i] = fmaf(ws, bf16_to_f(x1[i]), acc[8 + i]);
            }
        }
        float* orow = out + ((size_t)n * NW + w0 + wl) * CC + u0;
        #pragma unroll
        for (int i = 0; i < 4; ++i)
            *reinterpret_cast<float4*>(orow + i * 4) = *reinterpret_cast<const float4*>(&acc[i * 4]);
    }
}

extern "C" void kernel_launch(void* const* d_in, const int* in_sizes, int n_in,
                              void* d_out, int out_size, void* d_ws, size_t ws_size,
                              hipStream_t stream) {
    const float* x  = (const float*)d_in[0];
    const float* Wq = (const float*)d_in[1];
    const float* Wk = (const float*)d_in[2];
    const float* v  = (const float*)d_in[3];
    const float* b  = (const float*)d_in[4];
    float* out = (float*)d_out;

    ushort* WkT = (ushort*)d_ws;                   // combined [512][256] bf16
    ushort* WqT = WkT + (size_t)CC * UU;

    transpose_w<<<dim3(8, 8, 2), 256, 0, stream>>>(Wk, Wq, WkT, WqT);
    fused_smoother<<<NB * JB, 512, 0, stream>>>(x, WkT, v, b, out);
}